// Round 16
// baseline (336.872 us; speedup 1.0000x reference)
//
#include <hip/hip_runtime.h>
#include <hip/hip_bf16.h>
#include <math.h>

#define B_SZ   1024
#define CIN    96
#define COUT   12
#define LSEQ   32
#define DM     128
#define D_IN   256
#define D_ST   16
#define NH     8
#define HD     32
#define CONVD  288
#define EPROJ  552
#define EPSV   1e-5f

#define THREADS 512

typedef unsigned short ushort_t;
typedef unsigned int uint_t;
typedef __attribute__((ext_vector_type(8))) short short8;
typedef __attribute__((ext_vector_type(4))) float f32x4;

// ---- fragment-packed bf16 weights (device globals, rewritten each call) ----
#define NIP (4*35*4*512)   // in_proj: 4 layers x 35 ntiles x 4 kchunks x 512
#define NOP (4*8*8*512)    // out_proj: 4 x 8 x 8 x 512
#define NFC (8*3*512)      // fc_in:   8 ntiles x 3 kchunks x 512
__device__ ushort_t g_wip[NIP];
__device__ ushort_t g_wop[NOP];
__device__ ushort_t g_wfc[NFC];

// HW RNE bf16 conversion: D[15:0]=bf16(lo), D[31:16]=bf16(hi). 1 VALU instr.
__device__ __forceinline__ uint_t cvt2bf(float lo, float hi) {
    uint_t r;
    asm("v_cvt_pk_bf16_f32 %0, %1, %2" : "=v"(r) : "v"(lo), "v"(hi));
    return r;
}
__device__ __forceinline__ ushort_t f2bf(float f) {
    return (ushort_t)cvt2bf(f, f);
}
__device__ __forceinline__ float bf2f(ushort_t u) {
    return __uint_as_float((uint_t)u << 16);
}
__device__ __forceinline__ float siluf(float v) { return v / (1.f + __expf(-v)); }
__device__ __forceinline__ float softplusf_(float v) {
    return (v > 20.f) ? v : log1pf(__expf(v));
}

// prep kernel keeps the bit-exact software RNE (not perf-critical)
__device__ __forceinline__ ushort_t f2bf_sw(float f) {
    uint_t u = __float_as_uint(f);
    u += 0x7FFFu + ((u >> 16) & 1u);
    return (ushort_t)(u >> 16);
}

__global__ void prep_weights(const float* __restrict__ in_proj_w,
                             const float* __restrict__ out_proj_w,
                             const float* __restrict__ fc_in_w) {
    int idx = blockIdx.x * 256 + threadIdx.x;
    if (idx < NIP) {
        int f = idx >> 9, r = idx & 511;
        int l = r >> 3, j = r & 7;
        int li = f / 140, rem = f - li * 140;
        int nt = rem >> 2, kc = rem & 3;
        int e = nt * 16 + (l & 15);
        int d = kc * 32 + ((l >> 4) << 3) + j;
        float v = (e < EPROJ) ? in_proj_w[((size_t)li * EPROJ + e) * DM + d] : 0.f;
        g_wip[idx] = f2bf_sw(v);
    } else if (idx < NIP + NOP) {
        int i2 = idx - NIP;
        int f = i2 >> 9, r = i2 & 511;
        int l = r >> 3, j = r & 7;
        int li = f >> 6, rem = f & 63;
        int nt = rem >> 3, kc = rem & 7;
        int d = nt * 16 + (l & 15);
        int e = kc * 32 + ((l >> 4) << 3) + j;
        g_wop[i2] = f2bf_sw(out_proj_w[((size_t)li * DM + d) * D_IN + e]);
    } else if (idx < NIP + NOP + NFC) {
        int i2 = idx - NIP - NOP;
        int f = i2 >> 9, r = i2 & 511;
        int l = r >> 3, j = r & 7;
        int nt = f / 3, kc = f - nt * 3;
        int d = nt * 16 + (l & 15);
        int c = kc * 32 + ((l >> 4) << 3) + j;
        g_wfc[i2] = f2bf_sw(fc_in_w[d * CIN + c]);
    }
}

// init out_y with the dir-independent bias: fc_out_b[o]*sum_t(outlin[t]) + out_lin_b
__global__ void init_out(const float* __restrict__ fc_out_b,
                         const float* __restrict__ out_lin_w,
                         const float* __restrict__ out_lin_b,
                         float* __restrict__ out_y) {
    int i = blockIdx.x * 256 + threadIdx.x;
    if (i >= B_SZ * COUT) return;
    int o = i % COUT;
    float s = 0.f;
#pragma unroll
    for (int t = 0; t < LSEQ; ++t) s += out_lin_w[t];
    out_y[i] = fc_out_b[o] * s + out_lin_b[0];
}

// ---- LDS arena (f32 words), total 18176 words = 72704 B  (2 blocks/CU) ----
#define OFF_HH   0       // f32 [32][132]
#define OFF_BUFB 4224    // bf16 [32][128] (swizzled)
#define OFF_HNB  6272    // bf16 [32][128] (swizzled)
#define OFF_ZYB  8320    // bf16 [32][256] (swizzled), holds silu(z) then gated y
#define OFF_XB   12416   // bf16 [32][256] (swizzled)
#define OFF_BCF  16512   // f32 [32][36]
#define OFF_DTA  17664   // f32 [32][8][2]  (dt, dA) interleaved
#define SMEM_WORDS 18176
#define SMEM_BYTES (SMEM_WORDS * 4)

// s_xb / s_zyb swizzle: spread t-rows across bank groups (8-granule aligned)
#define XBI(t, c) (((t) * 256 + (c)) ^ (((t) & 7) << 3))

__global__ __launch_bounds__(THREADS, 4)
void mamba_fused(const float* __restrict__ x,
                 const float* __restrict__ buffer,
                 const float* __restrict__ fc_in_b,
                 const float* __restrict__ blk_norm_w,
                 const float* __restrict__ conv_w,
                 const float* __restrict__ conv_b,
                 const float* __restrict__ dt_bias,
                 const float* __restrict__ A_log,
                 const float* __restrict__ D_skip,
                 const float* __restrict__ mixer_norm_w,
                 const float* __restrict__ norm_f_w,
                 const float* __restrict__ fc_out_w,
                 const float* __restrict__ out_lin_w,
                 float* __restrict__ out_y,
                 float* __restrict__ out_buf)
{
    const int b   = blockIdx.x >> 1;
    const int dir = blockIdx.x & 1;
    const int tid = threadIdx.x;

    extern __shared__ float sm[];
    float*    s_hh  = sm + OFF_HH;
    ushort_t* s_bufb= (ushort_t*)(sm + OFF_BUFB);
    ushort_t* s_hnb = (ushort_t*)(sm + OFF_HNB);
    ushort_t* s_zyb = (ushort_t*)(sm + OFF_ZYB);
    ushort_t* s_xb  = (ushort_t*)(sm + OFF_XB);
    float*    s_bcf = sm + OFF_BCF;
    float*    s_dtA = sm + OFF_DTA;

    const int wid  = tid >> 6;
    const int lane = tid & 63;
    const int quad = lane >> 4;

    // ---- P1: shifted buffer -> s_bufb (bf16, swizzled); dir0 also writes out_buf ----
    {
        const float* bufp = buffer + (size_t)b * (CIN * LSEQ);
        const float* xp   = x + (size_t)b * CIN;
        float* obp        = out_buf + (size_t)b * (CIN * LSEQ);
        for (int i = tid; i < CIN * LSEQ; i += THREADS) {
            int c = i >> 5, l2 = i & 31;
            float v = (l2 < 31) ? bufp[i + 1] : xp[c];
            if (dir == 0) obp[i] = v;
            s_bufb[(l2 * 128 + c) ^ ((l2 & 7) << 3)] = f2bf(v);
        }
    }
    __syncthreads();

    // ---- fc_in via MFMA, write s_hh time-flipped for dir1 ----
    {
        int mt = wid >> 2, row = mt * 16 + (lane & 15);
        const short8* ab = (const short8*)s_bufb;
        const ushort_t* wb = g_wfc + lane * 8;
#pragma unroll
        for (int pass = 0; pass < 2; ++pass) {
            int nt = (wid & 3) + pass * 4;
            f32x4 acc = {0.f, 0.f, 0.f, 0.f};
#pragma unroll
            for (int kc = 0; kc < 3; ++kc) {
                short8 av = ab[(row * 16 + kc * 4 + quad) ^ (row & 7)];
                short8 bv = *(const short8*)(wb + (nt * 3 + kc) * 512);
                acc = __builtin_amdgcn_mfma_f32_16x16x32_bf16(av, bv, acc, 0, 0, 0);
            }
            int d = nt * 16 + (lane & 15);
            float bias = fc_in_b[d];
#pragma unroll
            for (int r = 0; r < 4; ++r) {
                int t = mt * 16 + quad * 4 + r;
                int tt = dir ? (31 - t) : t;
                s_hh[tt * 132 + d] = acc[r] + bias;
            }
        }
    }
    __syncthreads();

    for (int lyr = 0; lyr < 2; ++lyr) {
        const int li = dir * 2 + lyr;

        // (a) rmsnorm(s_hh) -> s_hnb (bf16, granule-swizzled)
        {
            int t = tid >> 4, sl = tid & 15;
            const float* row = s_hh + t * 132;
            float v[8]; float ss = 0.f;
#pragma unroll
            for (int j = 0; j < 8; ++j) { v[j] = row[sl * 8 + j]; ss += v[j] * v[j]; }
            ss += __shfl_xor(ss, 1); ss += __shfl_xor(ss, 2);
            ss += __shfl_xor(ss, 4); ss += __shfl_xor(ss, 8);
            float scale = rsqrtf(ss * (1.f / DM) + EPSV);
            const float* nw = blk_norm_w + li * DM;
            uint_t w[4];
#pragma unroll
            for (int p = 0; p < 4; ++p) {
                int d0 = sl * 8 + p * 2;
                w[p] = cvt2bf(v[p * 2] * scale * nw[d0],
                              v[p * 2 + 1] * scale * nw[d0 + 1]);
            }
            uint4 q = make_uint4(w[0], w[1], w[2], w[3]);
            ((uint4*)s_hnb)[(t * 16 + sl) ^ (t & 7)] = q;
        }
        __syncthreads();

        // (b) in_proj via MFMA; epilogue branch hoisted to wave-uniform nt
        {
            int mt = wid >> 2, row = mt * 16 + (lane & 15);
            const short8* ab = (const short8*)s_hnb;
            short8 a[4];
#pragma unroll
            for (int kc = 0; kc < 4; ++kc)
                a[kc] = ab[(row * 16 + kc * 4 + quad) ^ (row & 7)];

            const ushort_t* wbase = g_wip + (size_t)li * (35 * 4 * 512) + lane * 8;
            const int col = lane & 15;
            const int tbase = mt * 16 + quad * 4;
            for (int nt = wid & 3; nt < 35; nt += 4) {
                f32x4 acc = {0.f, 0.f, 0.f, 0.f};
#pragma unroll
                for (int kc = 0; kc < 4; ++kc) {
                    short8 bv = *(const short8*)(wbase + (nt * 4 + kc) * 512);
                    acc = __builtin_amdgcn_mfma_f32_16x16x32_bf16(a[kc], bv, acc, 0, 0, 0);
                }
                if (nt < 16) {                       // z segment
                    int e = nt * 16 + col;
#pragma unroll
                    for (int r = 0; r < 4; ++r) {
                        int t = tbase + r;
                        s_zyb[(t * 256 + e) ^ ((t & 7) << 3)] = f2bf(siluf(acc[r]));
                    }
                } else if (nt < 32) {                // x segment
                    int c = nt * 16 + col - D_IN;
#pragma unroll
                    for (int r = 0; r < 4; ++r) {
                        int t = tbase + r;
                        s_xb[XBI(t, c)] = f2bf(acc[r]);
                    }
                } else if (nt < 34) {                // B/C segment (f32)
                    int ch = nt * 16 + col - 512;
#pragma unroll
                    for (int r = 0; r < 4; ++r)
                        s_bcf[(tbase + r) * 36 + ch] = acc[r];
                } else {                             // dt segment (cols 0..7 only)
                    if (col < NH) {
                        float dtb  = dt_bias[li * NH + col];
                        float aneg = -__expf(A_log[li * NH + col]);
#pragma unroll
                        for (int r = 0; r < 4; ++r) {
                            int t = tbase + r;
                            float dtv = softplusf_(acc[r] + dtb);
                            s_dtA[t * 16 + col * 2]     = dtv;
                            s_dtA[t * 16 + col * 2 + 1] = __expf(dtv * aneg);
                        }
                    }
                }
            }
        }
        __syncthreads();

        // (c) causal depthwise conv + silu, IN PLACE (rolling window)
        if (tid < CONVD) {
            const int c = tid;
            const float4 wv = *(const float4*)(conv_w + ((size_t)li * CONVD + c) * 4);
            const float bias = conv_b[li * CONVD + c];
            float w0 = 0.f, w1 = 0.f, w2 = 0.f;
            if (c < D_IN) {
#pragma unroll
                for (int t = 0; t < 32; ++t) {
                    float cur = bf2f(s_xb[XBI(t, c)]);
                    float acc = bias + w0 * wv.x + w1 * wv.y + w2 * wv.z + cur * wv.w;
                    s_xb[XBI(t, c)] = f2bf(siluf(acc));
                    w0 = w1; w1 = w2; w2 = cur;
                }
            } else {
                const int ch = c - D_IN;
#pragma unroll
                for (int t = 0; t < 32; ++t) {
                    float cur = s_bcf[t * 36 + ch];
                    float acc = bias + w0 * wv.x + w1 * wv.y + w2 * wv.z + cur * wv.w;
                    s_bcf[t * 36 + ch] = siluf(acc);
                    w0 = w1; w1 = w2; w2 = cur;
                }
            }
        }
        __syncthreads();

        // (d) SSM scan, n-split: wave = head; lanes 0-31 own n=[0,8),
        //     lanes 32-63 own n=[8,16); xsv read is a same-address broadcast;
        //     one shfl_xor(32) combines; lanes<32 write y.
        {
            const int hd = wid;
            const int p  = lane & 31;
            const int nh = lane >> 5;
            float dsk = D_skip[li * NH + hd];
            float st[8];
#pragma unroll
            for (int n = 0; n < 8; ++n) st[n] = 0.f;
#pragma unroll
            for (int t = 0; t < 32; ++t) {
                const float2 da = *(const float2*)(s_dtA + t * 16 + hd * 2);
                float dtv = da.x, dAv = da.y;
                float xsv = bf2f(s_xb[XBI(t, hd * HD + p)]);
                float dtx = dtv * xsv;
                const f32x4* Bp = (const f32x4*)(s_bcf + t * 36 + nh * 8);
                const f32x4* Cp = (const f32x4*)(s_bcf + t * 36 + 16 + nh * 8);
                float acc0 = 0.f, acc1 = 0.f, acc2 = 0.f, acc3 = 0.f;
#pragma unroll
                for (int q = 0; q < 2; ++q) {
                    f32x4 Bv = Bp[q], Cv = Cp[q];
                    float* s4 = st + q * 4;
                    s4[0] = s4[0] * dAv + dtx * Bv.x;  acc0 += s4[0] * Cv.x;
                    s4[1] = s4[1] * dAv + dtx * Bv.y;  acc1 += s4[1] * Cv.y;
                    s4[2] = s4[2] * dAv + dtx * Bv.z;  acc2 += s4[2] * Cv.z;
                    s4[3] = s4[3] * dAv + dtx * Bv.w;  acc3 += s4[3] * Cv.w;
                }
                float acc = (acc0 + acc1) + (acc2 + acc3);
                acc += __shfl_xor(acc, 32);
                if (nh == 0)
                    s_xb[XBI(t, hd * HD + p)] = f2bf(acc + dsk * xsv);
            }
        }
        __syncthreads();

        // (e) gate + rmsnorm, contiguous-e mapping with b128 LDS accesses
        {
            int t = tid >> 4, sl = tid & 15;
            float g[16]; float ss = 0.f;
#pragma unroll
            for (int k = 0; k < 2; ++k) {
                int idx = XBI(t, sl * 16 + k * 8);       // 8-granule aligned
                short8 yv8 = *(const short8*)(s_xb + idx);
                short8 zv8 = *(const short8*)(s_zyb + idx);  // same swizzle formula
#pragma unroll
                for (int j = 0; j < 8; ++j) {
                    float yv = bf2f((ushort_t)yv8[j]);
                    float zv = bf2f((ushort_t)zv8[j]);   // already silu(z)
                    float gv = yv * zv;
                    g[k * 8 + j] = gv; ss += gv * gv;
                }
            }
            ss += __shfl_xor(ss, 1); ss += __shfl_xor(ss, 2);
            ss += __shfl_xor(ss, 4); ss += __shfl_xor(ss, 8);
            float scale = rsqrtf(ss * (1.f / D_IN) + EPSV);
            const float* mw = mixer_norm_w + li * D_IN + sl * 16;
#pragma unroll
            for (int k = 0; k < 2; ++k) {
                uint_t w[4];
#pragma unroll
                for (int p2 = 0; p2 < 4; ++p2) {
                    int j0 = k * 8 + p2 * 2;
                    w[p2] = cvt2bf(g[j0] * scale * mw[j0],
                                   g[j0 + 1] * scale * mw[j0 + 1]);
                }
                *(uint4*)(s_zyb + XBI(t, sl * 16 + k * 8)) =
                    make_uint4(w[0], w[1], w[2], w[3]);
            }
        }
        __syncthreads();

        // (f) out_proj via MFMA, residual accumulate into s_hh
        {
            int mt = wid >> 2, row = mt * 16 + (lane & 15);
            const short8* yb = (const short8*)s_zyb;
            const ushort_t* wb = g_wop + (size_t)li * (8 * 8 * 512) + lane * 8;
#pragma unroll
            for (int pass = 0; pass < 2; ++pass) {
                int nt = (wid & 3) + pass * 4;
                f32x4 acc = {0.f, 0.f, 0.f, 0.f};
#pragma unroll
                for (int kh = 0; kh < 2; ++kh) {
                    short8 a4[4];
#pragma unroll
                    for (int j = 0; j < 4; ++j)
                        a4[j] = yb[(row * 32 + (kh * 4 + j) * 4 + quad) ^ (row & 7)];
#pragma unroll
                    for (int j = 0; j < 4; ++j) {
                        short8 bv = *(const short8*)(wb + (nt * 8 + kh * 4 + j) * 512);
                        acc = __builtin_amdgcn_mfma_f32_16x16x32_bf16(a4[j], bv, acc, 0, 0, 0);
                    }
                }
                int d = nt * 16 + (lane & 15);
#pragma unroll
                for (int r = 0; r < 4; ++r)
                    s_hh[(mt * 16 + quad * 4 + r) * 132 + d] += acc[r];
            }
        }
        __syncthreads();
    } // lyr

    // ---- final rmsnorm(norm_f_w[dir]) IN PLACE on s_hh ----
    {
        int t = tid >> 4, sl = tid & 15;
        float* row = s_hh + t * 132;
        float v[8]; float ss = 0.f;
#pragma unroll
        for (int j = 0; j < 8; ++j) { v[j] = row[sl * 8 + j]; ss += v[j] * v[j]; }
        ss += __shfl_xor(ss, 1); ss += __shfl_xor(ss, 2);
        ss += __shfl_xor(ss, 4); ss += __shfl_xor(ss, 8);
        float scale = rsqrtf(ss * (1.f / DM) + EPSV);
        const float* nw = norm_f_w + dir * DM;
#pragma unroll
        for (int j = 0; j < 8; ++j) {
            int d = sl * 8 + j;
            row[d] = v[j] * scale * nw[d];
        }
    }
    __syncthreads();

    // ---- partial fc_out + out_lin reduction; atomicAdd into out_y ----
    if (tid < COUT * LSEQ) {
        int o = tid >> 5, t = tid & 31;          // t = local (possibly flipped) time
        int t_out = dir ? (31 - t) : t;          // global time index
        const float* wrow = fc_out_w + o * DM;
        const float* hrow = s_hh + t * 132;
        float acc = 0.f;
#pragma unroll
        for (int d = 0; d < DM; d += 4) {
            float4 wv = *(const float4*)(wrow + d);
            float4 hv = *(const float4*)(hrow + d);
            acc += hv.x * wv.x + hv.y * wv.y + hv.z * wv.z + hv.w * wv.w;
        }
        float part = acc * out_lin_w[t_out];
        part += __shfl_xor(part, 1);  part += __shfl_xor(part, 2);
        part += __shfl_xor(part, 4);  part += __shfl_xor(part, 8);
        part += __shfl_xor(part, 16);
        if (t == 0) atomicAdd(&out_y[b * COUT + o], part);
    }
}

extern "C" void kernel_launch(void* const* d_in, const int* in_sizes, int n_in,
                              void* d_out, int out_size, void* d_ws, size_t ws_size,
                              hipStream_t stream) {
    const float* x            = (const float*)d_in[0];
    const float* buffer      = (const float*)d_in[1];
    const float* fc_in_w     = (const float*)d_in[2];
    const float* fc_in_b     = (const float*)d_in[3];
    const float* blk_norm_w  = (const float*)d_in[4];
    const float* in_proj_w   = (const float*)d_in[5];
    const float* conv_w      = (const float*)d_in[6];
    const float* conv_b      = (const float*)d_in[7];
    const float* dt_bias     = (const float*)d_in[8];
    const float* A_log       = (const float*)d_in[9];
    const float* D_skip      = (const float*)d_in[10];
    const float* mixer_norm_w= (const float*)d_in[11];
    const float* out_proj_w  = (const float*)d_in[12];
    const float* norm_f_w    = (const float*)d_in[13];
    const float* fc_out_w    = (const float*)d_in[14];
    const float* fc_out_b    = (const float*)d_in[15];
    const float* out_lin_w   = (const float*)d_in[16];
    const float* out_lin_b   = (const float*)d_in[17];

    float* out_y   = (float*)d_out;
    float* out_buf = out_y + (size_t)B_SZ * COUT;

    prep_weights<<<(NIP + NOP + NFC + 255) / 256, 256, 0, stream>>>(
        in_proj_w, out_proj_w, fc_in_w);

    init_out<<<(B_SZ * COUT + 255) / 256, 256, 0, stream>>>(
        fc_out_b, out_lin_w, out_lin_b, out_y);

    (void)hipFuncSetAttribute((const void*)mamba_fused,
                              hipFuncAttributeMaxDynamicSharedMemorySize,
                              SMEM_BYTES);

    mamba_fused<<<B_SZ * 2, THREADS, SMEM_BYTES, stream>>>(
        x, buffer, fc_in_b, blk_norm_w, conv_w, conv_b,
        dt_bias, A_log, D_skip, mixer_norm_w, norm_f_w,
        fc_out_w, out_lin_w, out_y, out_buf);
}

// Round 17
// 238.894 us; speedup vs baseline: 1.4101x; 1.4101x over previous
//
#include <hip/hip_runtime.h>
#include <hip/hip_bf16.h>
#include <math.h>

#define B_SZ   1024
#define CIN    96
#define COUT   12
#define LSEQ   32
#define DM     128
#define D_IN   256
#define D_ST   16
#define NH     8
#define HD     32
#define CONVD  288
#define EPROJ  552
#define EPSV   1e-5f

#define THREADS 512

typedef unsigned short ushort_t;
typedef unsigned int uint_t;
typedef __attribute__((ext_vector_type(8))) short short8;
typedef __attribute__((ext_vector_type(4))) float f32x4;

// ---- fragment-packed bf16 weights (device globals, rewritten each call) ----
#define NIP (4*35*4*512)   // in_proj: 4 layers x 35 ntiles x 4 kchunks x 512
#define NOP (4*8*8*512)    // out_proj: 4 x 8 x 8 x 512
#define NFC (8*3*512)      // fc_in:   8 ntiles x 3 kchunks x 512
#define NOUT (B_SZ*COUT)   // out_y bias init, folded into prep
__device__ ushort_t g_wip[NIP];
__device__ ushort_t g_wop[NOP];
__device__ ushort_t g_wfc[NFC];

// HW RNE bf16 conversion: D[15:0]=bf16(lo), D[31:16]=bf16(hi). 1 VALU instr.
__device__ __forceinline__ uint_t cvt2bf(float lo, float hi) {
    uint_t r;
    asm("v_cvt_pk_bf16_f32 %0, %1, %2" : "=v"(r) : "v"(lo), "v"(hi));
    return r;
}
__device__ __forceinline__ ushort_t f2bf(float f) {
    return (ushort_t)cvt2bf(f, f);
}
__device__ __forceinline__ float bf2f(ushort_t u) {
    return __uint_as_float((uint_t)u << 16);
}
__device__ __forceinline__ float siluf(float v) { return v / (1.f + __expf(-v)); }
__device__ __forceinline__ float softplusf_(float v) {
    return (v > 20.f) ? v : log1pf(__expf(v));
}

// prep kernel keeps the bit-exact software RNE (not perf-critical)
__device__ __forceinline__ ushort_t f2bf_sw(float f) {
    uint_t u = __float_as_uint(f);
    u += 0x7FFFu + ((u >> 16) & 1u);
    return (ushort_t)(u >> 16);
}

__global__ void prep_weights(const float* __restrict__ in_proj_w,
                             const float* __restrict__ out_proj_w,
                             const float* __restrict__ fc_in_w,
                             const float* __restrict__ fc_out_b,
                             const float* __restrict__ out_lin_w,
                             const float* __restrict__ out_lin_b,
                             float* __restrict__ out_y) {
    int idx = blockIdx.x * 256 + threadIdx.x;
    if (idx < NIP) {
        int f = idx >> 9, r = idx & 511;
        int l = r >> 3, j = r & 7;
        int li = f / 140, rem = f - li * 140;
        int nt = rem >> 2, kc = rem & 3;
        int e = nt * 16 + (l & 15);
        int d = kc * 32 + ((l >> 4) << 3) + j;
        float v = (e < EPROJ) ? in_proj_w[((size_t)li * EPROJ + e) * DM + d] : 0.f;
        g_wip[idx] = f2bf_sw(v);
    } else if (idx < NIP + NOP) {
        int i2 = idx - NIP;
        int f = i2 >> 9, r = i2 & 511;
        int l = r >> 3, j = r & 7;
        int li = f >> 6, rem = f & 63;
        int nt = rem >> 3, kc = rem & 7;
        int d = nt * 16 + (l & 15);
        int e = kc * 32 + ((l >> 4) << 3) + j;
        g_wop[i2] = f2bf_sw(out_proj_w[((size_t)li * DM + d) * D_IN + e]);
    } else if (idx < NIP + NOP + NFC) {
        int i2 = idx - NIP - NOP;
        int f = i2 >> 9, r = i2 & 511;
        int l = r >> 3, j = r & 7;
        int nt = f / 3, kc = f - nt * 3;
        int d = nt * 16 + (l & 15);
        int c = kc * 32 + ((l >> 4) << 3) + j;
        g_wfc[i2] = f2bf_sw(fc_in_w[d * CIN + c]);
    } else if (idx < NIP + NOP + NFC + NOUT) {
        int i2 = idx - NIP - NOP - NFC;
        int o = i2 % COUT;
        float s = 0.f;
#pragma unroll
        for (int t = 0; t < LSEQ; ++t) s += out_lin_w[t];
        out_y[i2] = fc_out_b[o] * s + out_lin_b[0];
    }
}

// ---- LDS arena (f32 words), total 18176 words = 72704 B  (2 blocks/CU) ----
#define OFF_HH   0       // f32 [32][132]
#define OFF_BUFB 4224    // bf16 [32][128] (swizzled)
#define OFF_HNB  6272    // bf16 [32][128] (swizzled)
#define OFF_ZYB  8320    // bf16 [32][256] (swizzled), holds silu(z) then gated y
#define OFF_XB   12416   // bf16 [32][256] (swizzled)
#define OFF_BCF  16512   // f32 [32][36]
#define OFF_DTA  17664   // f32 [32][8][2]  (dt, dA) interleaved
#define SMEM_WORDS 18176
#define SMEM_BYTES (SMEM_WORDS * 4)

// s_xb / s_zyb swizzle: spread t-rows across bank groups (8-granule aligned)
#define XBI(t, c) (((t) * 256 + (c)) ^ (((t) & 7) << 3))

__global__ __launch_bounds__(THREADS, 4)
void mamba_fused(const float* __restrict__ x,
                 const float* __restrict__ buffer,
                 const float* __restrict__ fc_in_b,
                 const float* __restrict__ blk_norm_w,
                 const float* __restrict__ conv_w,
                 const float* __restrict__ conv_b,
                 const float* __restrict__ dt_bias,
                 const float* __restrict__ A_log,
                 const float* __restrict__ D_skip,
                 const float* __restrict__ mixer_norm_w,
                 const float* __restrict__ norm_f_w,
                 const float* __restrict__ fc_out_w,
                 const float* __restrict__ out_lin_w,
                 float* __restrict__ out_y,
                 float* __restrict__ out_buf)
{
    const int b   = blockIdx.x >> 1;
    const int dir = blockIdx.x & 1;
    const int tid = threadIdx.x;

    extern __shared__ float sm[];
    float*    s_hh  = sm + OFF_HH;
    ushort_t* s_bufb= (ushort_t*)(sm + OFF_BUFB);
    ushort_t* s_hnb = (ushort_t*)(sm + OFF_HNB);
    ushort_t* s_zyb = (ushort_t*)(sm + OFF_ZYB);
    ushort_t* s_xb  = (ushort_t*)(sm + OFF_XB);
    float*    s_bcf = sm + OFF_BCF;
    float*    s_dtA = sm + OFF_DTA;

    const int wid  = tid >> 6;
    const int lane = tid & 63;
    const int quad = lane >> 4;

    // ---- P1: shifted buffer -> s_bufb (bf16, swizzled); dir0 also writes out_buf ----
    {
        const float* bufp = buffer + (size_t)b * (CIN * LSEQ);
        const float* xp   = x + (size_t)b * CIN;
        float* obp        = out_buf + (size_t)b * (CIN * LSEQ);
        for (int i = tid; i < CIN * LSEQ; i += THREADS) {
            int c = i >> 5, l2 = i & 31;
            float v = (l2 < 31) ? bufp[i + 1] : xp[c];
            if (dir == 0) obp[i] = v;
            s_bufb[(l2 * 128 + c) ^ ((l2 & 7) << 3)] = f2bf(v);
        }
    }
    __syncthreads();

    // ---- fc_in via MFMA, write s_hh time-flipped for dir1 ----
    {
        int mt = wid >> 2, row = mt * 16 + (lane & 15);
        const short8* ab = (const short8*)s_bufb;
        const ushort_t* wb = g_wfc + lane * 8;
#pragma unroll
        for (int pass = 0; pass < 2; ++pass) {
            int nt = (wid & 3) + pass * 4;
            f32x4 acc = {0.f, 0.f, 0.f, 0.f};
#pragma unroll
            for (int kc = 0; kc < 3; ++kc) {
                short8 av = ab[(row * 16 + kc * 4 + quad) ^ (row & 7)];
                short8 bv = *(const short8*)(wb + (nt * 3 + kc) * 512);
                acc = __builtin_amdgcn_mfma_f32_16x16x32_bf16(av, bv, acc, 0, 0, 0);
            }
            int d = nt * 16 + (lane & 15);
            float bias = fc_in_b[d];
#pragma unroll
            for (int r = 0; r < 4; ++r) {
                int t = mt * 16 + quad * 4 + r;
                int tt = dir ? (31 - t) : t;
                s_hh[tt * 132 + d] = acc[r] + bias;
            }
        }
    }
    __syncthreads();

    for (int lyr = 0; lyr < 2; ++lyr) {
        const int li = dir * 2 + lyr;

        // (a) rmsnorm(s_hh) -> s_hnb (bf16, granule-swizzled)
        {
            int t = tid >> 4, sl = tid & 15;
            const float* row = s_hh + t * 132;
            float v[8]; float ss = 0.f;
#pragma unroll
            for (int j = 0; j < 8; ++j) { v[j] = row[sl * 8 + j]; ss += v[j] * v[j]; }
            ss += __shfl_xor(ss, 1); ss += __shfl_xor(ss, 2);
            ss += __shfl_xor(ss, 4); ss += __shfl_xor(ss, 8);
            float scale = rsqrtf(ss * (1.f / DM) + EPSV);
            const float* nw = blk_norm_w + li * DM;
            uint_t w[4];
#pragma unroll
            for (int p = 0; p < 4; ++p) {
                int d0 = sl * 8 + p * 2;
                w[p] = cvt2bf(v[p * 2] * scale * nw[d0],
                              v[p * 2 + 1] * scale * nw[d0 + 1]);
            }
            uint4 q = make_uint4(w[0], w[1], w[2], w[3]);
            ((uint4*)s_hnb)[(t * 16 + sl) ^ (t & 7)] = q;
        }
        __syncthreads();

        // (b) in_proj via MFMA; epilogue branch hoisted to wave-uniform nt
        {
            int mt = wid >> 2, row = mt * 16 + (lane & 15);
            const short8* ab = (const short8*)s_hnb;
            short8 a[4];
#pragma unroll
            for (int kc = 0; kc < 4; ++kc)
                a[kc] = ab[(row * 16 + kc * 4 + quad) ^ (row & 7)];

            const ushort_t* wbase = g_wip + (size_t)li * (35 * 4 * 512) + lane * 8;
            const int col = lane & 15;
            const int tbase = mt * 16 + quad * 4;
            for (int nt = wid & 3; nt < 35; nt += 4) {
                f32x4 acc = {0.f, 0.f, 0.f, 0.f};
#pragma unroll
                for (int kc = 0; kc < 4; ++kc) {
                    short8 bv = *(const short8*)(wbase + (nt * 4 + kc) * 512);
                    acc = __builtin_amdgcn_mfma_f32_16x16x32_bf16(a[kc], bv, acc, 0, 0, 0);
                }
                if (nt < 16) {                       // z segment
                    int e = nt * 16 + col;
#pragma unroll
                    for (int r = 0; r < 4; ++r) {
                        int t = tbase + r;
                        s_zyb[(t * 256 + e) ^ ((t & 7) << 3)] = f2bf(siluf(acc[r]));
                    }
                } else if (nt < 32) {                // x segment
                    int c = nt * 16 + col - D_IN;
#pragma unroll
                    for (int r = 0; r < 4; ++r) {
                        int t = tbase + r;
                        s_xb[XBI(t, c)] = f2bf(acc[r]);
                    }
                } else if (nt < 34) {                // B/C segment (f32)
                    int ch = nt * 16 + col - 512;
#pragma unroll
                    for (int r = 0; r < 4; ++r)
                        s_bcf[(tbase + r) * 36 + ch] = acc[r];
                } else {                             // dt segment (cols 0..7 only)
                    if (col < NH) {
                        float dtb  = dt_bias[li * NH + col];
                        float aneg = -__expf(A_log[li * NH + col]);
#pragma unroll
                        for (int r = 0; r < 4; ++r) {
                            int t = tbase + r;
                            float dtv = softplusf_(acc[r] + dtb);
                            s_dtA[t * 16 + col * 2]     = dtv;
                            s_dtA[t * 16 + col * 2 + 1] = __expf(dtv * aneg);
                        }
                    }
                }
            }
        }
        __syncthreads();

        // (c) causal depthwise conv + silu, IN PLACE (rolling window)
        if (tid < CONVD) {
            const int c = tid;
            const float4 wv = *(const float4*)(conv_w + ((size_t)li * CONVD + c) * 4);
            const float bias = conv_b[li * CONVD + c];
            float w0 = 0.f, w1 = 0.f, w2 = 0.f;
            if (c < D_IN) {
#pragma unroll
                for (int t = 0; t < 32; ++t) {
                    float cur = bf2f(s_xb[XBI(t, c)]);
                    float acc = bias + w0 * wv.x + w1 * wv.y + w2 * wv.z + cur * wv.w;
                    s_xb[XBI(t, c)] = f2bf(siluf(acc));
                    w0 = w1; w1 = w2; w2 = cur;
                }
            } else {
                const int ch = c - D_IN;
#pragma unroll
                for (int t = 0; t < 32; ++t) {
                    float cur = s_bcf[t * 36 + ch];
                    float acc = bias + w0 * wv.x + w1 * wv.y + w2 * wv.z + cur * wv.w;
                    s_bcf[t * 36 + ch] = siluf(acc);
                    w0 = w1; w1 = w2; w2 = cur;
                }
            }
        }
        __syncthreads();

        // (d) SSM scan: thread=(head,p); dt/dA preloaded pair; y -> s_xb (bf16)
        if (tid < 256) {
            int hd = tid >> 5, p = tid & 31;
            float dsk = D_skip[li * NH + hd];
            float st[16];
#pragma unroll
            for (int n = 0; n < 16; ++n) st[n] = 0.f;
#pragma unroll
            for (int t = 0; t < 32; ++t) {
                const float2 da = *(const float2*)(s_dtA + t * 16 + hd * 2);
                float dtv = da.x, dAv = da.y;
                float xsv = bf2f(s_xb[XBI(t, hd * HD + p)]);
                float dtx = dtv * xsv;
                const f32x4* Bp = (const f32x4*)(s_bcf + t * 36);
                const f32x4* Cp = (const f32x4*)(s_bcf + t * 36 + 16);
                float acc0 = 0.f, acc1 = 0.f, acc2 = 0.f, acc3 = 0.f;
#pragma unroll
                for (int q = 0; q < 4; ++q) {
                    f32x4 Bv = Bp[q], Cv = Cp[q];
                    float* s4 = st + q * 4;
                    s4[0] = s4[0] * dAv + dtx * Bv.x;  acc0 += s4[0] * Cv.x;
                    s4[1] = s4[1] * dAv + dtx * Bv.y;  acc1 += s4[1] * Cv.y;
                    s4[2] = s4[2] * dAv + dtx * Bv.z;  acc2 += s4[2] * Cv.z;
                    s4[3] = s4[3] * dAv + dtx * Bv.w;  acc3 += s4[3] * Cv.w;
                }
                float y = (acc0 + acc1) + (acc2 + acc3) + dsk * xsv;
                s_xb[XBI(t, hd * HD + p)] = f2bf(y);
            }
        }
        __syncthreads();

        // (e) gate + rmsnorm, contiguous-e mapping with b128 LDS accesses
        {
            int t = tid >> 4, sl = tid & 15;
            float g[16]; float ss = 0.f;
#pragma unroll
            for (int k = 0; k < 2; ++k) {
                int idx = XBI(t, sl * 16 + k * 8);       // 8-granule aligned
                short8 yv8 = *(const short8*)(s_xb + idx);
                short8 zv8 = *(const short8*)(s_zyb + idx);  // same swizzle formula
#pragma unroll
                for (int j = 0; j < 8; ++j) {
                    float yv = bf2f((ushort_t)yv8[j]);
                    float zv = bf2f((ushort_t)zv8[j]);   // already silu(z)
                    float gv = yv * zv;
                    g[k * 8 + j] = gv; ss += gv * gv;
                }
            }
            ss += __shfl_xor(ss, 1); ss += __shfl_xor(ss, 2);
            ss += __shfl_xor(ss, 4); ss += __shfl_xor(ss, 8);
            float scale = rsqrtf(ss * (1.f / D_IN) + EPSV);
            const float* mw = mixer_norm_w + li * D_IN + sl * 16;
#pragma unroll
            for (int k = 0; k < 2; ++k) {
                uint_t w[4];
#pragma unroll
                for (int p2 = 0; p2 < 4; ++p2) {
                    int j0 = k * 8 + p2 * 2;
                    w[p2] = cvt2bf(g[j0] * scale * mw[j0],
                                   g[j0 + 1] * scale * mw[j0 + 1]);
                }
                *(uint4*)(s_zyb + XBI(t, sl * 16 + k * 8)) =
                    make_uint4(w[0], w[1], w[2], w[3]);
            }
        }
        __syncthreads();

        // (f) out_proj via MFMA, residual accumulate into s_hh
        {
            int mt = wid >> 2, row = mt * 16 + (lane & 15);
            const short8* yb = (const short8*)s_zyb;
            const ushort_t* wb = g_wop + (size_t)li * (8 * 8 * 512) + lane * 8;
#pragma unroll
            for (int pass = 0; pass < 2; ++pass) {
                int nt = (wid & 3) + pass * 4;
                f32x4 acc = {0.f, 0.f, 0.f, 0.f};
#pragma unroll
                for (int kh = 0; kh < 2; ++kh) {
                    short8 a4[4];
#pragma unroll
                    for (int j = 0; j < 4; ++j)
                        a4[j] = yb[(row * 32 + (kh * 4 + j) * 4 + quad) ^ (row & 7)];
#pragma unroll
                    for (int j = 0; j < 4; ++j) {
                        short8 bv = *(const short8*)(wb + (nt * 8 + kh * 4 + j) * 512);
                        acc = __builtin_amdgcn_mfma_f32_16x16x32_bf16(a4[j], bv, acc, 0, 0, 0);
                    }
                }
                int d = nt * 16 + (lane & 15);
#pragma unroll
                for (int r = 0; r < 4; ++r)
                    s_hh[(mt * 16 + quad * 4 + r) * 132 + d] += acc[r];
            }
        }
        __syncthreads();
    } // lyr

    // ---- final rmsnorm(norm_f_w[dir]) IN PLACE on s_hh ----
    {
        int t = tid >> 4, sl = tid & 15;
        float* row = s_hh + t * 132;
        float v[8]; float ss = 0.f;
#pragma unroll
        for (int j = 0; j < 8; ++j) { v[j] = row[sl * 8 + j]; ss += v[j] * v[j]; }
        ss += __shfl_xor(ss, 1); ss += __shfl_xor(ss, 2);
        ss += __shfl_xor(ss, 4); ss += __shfl_xor(ss, 8);
        float scale = rsqrtf(ss * (1.f / DM) + EPSV);
        const float* nw = norm_f_w + dir * DM;
#pragma unroll
        for (int j = 0; j < 8; ++j) {
            int d = sl * 8 + j;
            row[d] = v[j] * scale * nw[d];
        }
    }
    __syncthreads();

    // ---- partial fc_out + out_lin reduction; atomicAdd into out_y ----
    if (tid < COUT * LSEQ) {
        int o = tid >> 5, t = tid & 31;          // t = local (possibly flipped) time
        int t_out = dir ? (31 - t) : t;          // global time index
        const float* wrow = fc_out_w + o * DM;
        const float* hrow = s_hh + t * 132;
        float acc = 0.f;
#pragma unroll
        for (int d = 0; d < DM; d += 4) {
            float4 wv = *(const float4*)(wrow + d);
            float4 hv = *(const float4*)(hrow + d);
            acc += hv.x * wv.x + hv.y * wv.y + hv.z * wv.z + hv.w * wv.w;
        }
        float part = acc * out_lin_w[t_out];
        part += __shfl_xor(part, 1);  part += __shfl_xor(part, 2);
        part += __shfl_xor(part, 4);  part += __shfl_xor(part, 8);
        part += __shfl_xor(part, 16);
        if (t == 0) atomicAdd(&out_y[b * COUT + o], part);
    }
}

extern "C" void kernel_launch(void* const* d_in, const int* in_sizes, int n_in,
                              void* d_out, int out_size, void* d_ws, size_t ws_size,
                              hipStream_t stream) {
    const float* x            = (const float*)d_in[0];
    const float* buffer      = (const float*)d_in[1];
    const float* fc_in_w     = (const float*)d_in[2];
    const float* fc_in_b     = (const float*)d_in[3];
    const float* blk_norm_w  = (const float*)d_in[4];
    const float* in_proj_w   = (const float*)d_in[5];
    const float* conv_w      = (const float*)d_in[6];
    const float* conv_b      = (const float*)d_in[7];
    const float* dt_bias     = (const float*)d_in[8];
    const float* A_log       = (const float*)d_in[9];
    const float* D_skip      = (const float*)d_in[10];
    const float* mixer_norm_w= (const float*)d_in[11];
    const float* out_proj_w  = (const float*)d_in[12];
    const float* norm_f_w    = (const float*)d_in[13];
    const float* fc_out_w    = (const float*)d_in[14];
    const float* fc_out_b    = (const float*)d_in[15];
    const float* out_lin_w   = (const float*)d_in[16];
    const float* out_lin_b   = (const float*)d_in[17];

    float* out_y   = (float*)d_out;
    float* out_buf = out_y + (size_t)B_SZ * COUT;

    prep_weights<<<(NIP + NOP + NFC + NOUT + 255) / 256, 256, 0, stream>>>(
        in_proj_w, out_proj_w, fc_in_w, fc_out_b, out_lin_w, out_lin_b, out_y);

    (void)hipFuncSetAttribute((const void*)mamba_fused,
                              hipFuncAttributeMaxDynamicSharedMemorySize,
                              SMEM_BYTES);

    mamba_fused<<<B_SZ * 2, THREADS, SMEM_BYTES, stream>>>(
        x, buffer, fc_in_b, blk_norm_w, conv_w, conv_b,
        dt_bias, A_log, D_skip, mixer_norm_w, norm_f_w,
        fc_out_w, out_lin_w, out_y, out_buf);
}